// Round 6
// baseline (1072.114 us; speedup 1.0000x reference)
//
#include <hip/hip_runtime.h>
#include <hip/hip_fp16.h>
#include <math.h>

#define N_NODES 100000
#define N_EDGES 400000
#define HDIM    128
#define KP1     6      // K+1 coefficients per group
#define RMS_EPS 1.1920929e-07f

#define SCAN_B  256
#define N_SCAN_BLOCKS ((N_NODES + SCAN_B - 1) / SCAN_B)   // 391
#define NBUCKETS 64

// native clang vector types for nontemporal builtins
typedef int   intx4   __attribute__((ext_vector_type(4)));
typedef float floatx4 __attribute__((ext_vector_type(4)));

// ---------------------------------------------------------------------------
// degree histogram of destinations
// ---------------------------------------------------------------------------
__global__ void hist_kernel(const int* __restrict__ dst, int* __restrict__ deg) {
    int e = blockIdx.x * blockDim.x + threadIdx.x;
    if (e >= N_EDGES) return;
    atomicAdd(&deg[dst[e]], 1);
}

// ---------------------------------------------------------------------------
// bucket count by degree (clamped to NBUCKETS-1)
// ---------------------------------------------------------------------------
__global__ void bucket_count_kernel(const int* __restrict__ deg, int* __restrict__ bcount) {
    int i = blockIdx.x * blockDim.x + threadIdx.x;
    if (i >= N_NODES) return;
    int d = deg[i];
    int b = d < NBUCKETS ? d : NBUCKETS - 1;
    atomicAdd(&bcount[b], 1);
}

// ---------------------------------------------------------------------------
// exclusive scan of 64 bucket counts -> bucket cursors (single block)
// ---------------------------------------------------------------------------
__global__ void bucket_scan_kernel(const int* __restrict__ bcount, int* __restrict__ bcursor) {
    __shared__ int lds[NBUCKETS];
    int v = bcount[threadIdx.x];
    lds[threadIdx.x] = v;
    __syncthreads();
    #pragma unroll
    for (int off = 1; off < NBUCKETS; off <<= 1) {
        int t = ((int)threadIdx.x >= off) ? lds[threadIdx.x - off] : 0;
        __syncthreads();
        lds[threadIdx.x] += t;
        __syncthreads();
    }
    bcursor[threadIdx.x] = lds[threadIdx.x] - v;   // exclusive
}

// ---------------------------------------------------------------------------
// counting-sort assignment: sorted position per node
// ---------------------------------------------------------------------------
__global__ void assign_kernel(const int* __restrict__ deg,
                              int* __restrict__ bcursor,
                              int* __restrict__ perm,
                              int* __restrict__ sortpos,
                              int* __restrict__ degs_sorted) {
    int i = blockIdx.x * blockDim.x + threadIdx.x;
    if (i >= N_NODES) return;
    int d = deg[i];
    int b = d < NBUCKETS ? d : NBUCKETS - 1;
    int pos = atomicAdd(&bcursor[b], 1);
    perm[pos] = i;
    sortpos[i] = pos;
    degs_sorted[pos] = d;
}

// ---------------------------------------------------------------------------
// per-block inclusive scan of sorted degrees
// ---------------------------------------------------------------------------
__global__ void scan_local_kernel(const int* __restrict__ degs,
                                  int* __restrict__ inc,
                                  int* __restrict__ blockSums) {
    __shared__ int lds[SCAN_B];
    int i = blockIdx.x * SCAN_B + threadIdx.x;
    int v = (i < N_NODES) ? degs[i] : 0;
    lds[threadIdx.x] = v;
    __syncthreads();
    #pragma unroll
    for (int off = 1; off < SCAN_B; off <<= 1) {
        int t = (threadIdx.x >= off) ? lds[threadIdx.x - off] : 0;
        __syncthreads();
        lds[threadIdx.x] += t;
        __syncthreads();
    }
    if (i < N_NODES) inc[i] = lds[threadIdx.x];
    if (threadIdx.x == SCAN_B - 1) blockSums[blockIdx.x] = lds[SCAN_B - 1];
}

// ---------------------------------------------------------------------------
// exclusive scan of the 391 block sums (single block)
// ---------------------------------------------------------------------------
__global__ void scan_blocks_kernel(int* __restrict__ blockSums) {
    __shared__ int lds[512];
    int v = (threadIdx.x < N_SCAN_BLOCKS) ? blockSums[threadIdx.x] : 0;
    lds[threadIdx.x] = v;
    __syncthreads();
    #pragma unroll
    for (int off = 1; off < 512; off <<= 1) {
        int t = ((int)threadIdx.x >= off) ? lds[threadIdx.x - off] : 0;
        __syncthreads();
        lds[threadIdx.x] += t;
        __syncthreads();
    }
    if (threadIdx.x < N_SCAN_BLOCKS)
        blockSums[threadIdx.x] = (threadIdx.x == 0) ? 0 : lds[threadIdx.x - 1];
}

// ---------------------------------------------------------------------------
// rowptr2 (exclusive, sorted order) + cursor copy
// ---------------------------------------------------------------------------
__global__ void finalize_kernel(const int* __restrict__ degs_sorted,
                                const int* __restrict__ inc,
                                const int* __restrict__ blockSums,
                                int* __restrict__ rowptr2,
                                int* __restrict__ cur2) {
    int i = blockIdx.x * SCAN_B + threadIdx.x;
    if (i >= N_NODES) return;
    int ex = inc[i] - degs_sorted[i] + blockSums[i >> 8];
    rowptr2[i] = ex;
    cur2[i] = ex;
    if (i == 0) rowptr2[N_NODES] = N_EDGES;
}

// ---------------------------------------------------------------------------
// fill packed (src_row_offset, weight), edge slots contiguous in sorted order
// ---------------------------------------------------------------------------
__global__ void fill_kernel(const int* __restrict__ src,
                            const int* __restrict__ dst,
                            const float* __restrict__ ew,
                            const int* __restrict__ sortpos,
                            int* __restrict__ cur2,
                            int2* __restrict__ epack) {
    int e = blockIdx.x * blockDim.x + threadIdx.x;
    if (e >= N_EDGES) return;
    int sp = sortpos[dst[e]];
    int pos = atomicAdd(&cur2[sp], 1);
    int2 p;
    p.x = src[e] * HDIM;                 // element offset of source row
    p.y = __float_as_int(ew[e]);
    epack[pos] = p;
}

// ---------------------------------------------------------------------------
// helpers: 8-dim fragments per lane; gathers use non-temporal loads
// ---------------------------------------------------------------------------
__device__ __forceinline__ void fma8_h_nt(const __half* __restrict__ p, float w, float* S) {
    intx4 r = __builtin_nontemporal_load(reinterpret_cast<const intx4*>(p));
    union { intx4 v; __half2 h[4]; } u;
    u.v = r;
    #pragma unroll
    for (int q = 0; q < 4; ++q) {
        float2 f = __half22float2(u.h[q]);
        S[2 * q + 0] += w * f.x;
        S[2 * q + 1] += w * f.y;
    }
}
__device__ __forceinline__ void fma8_f_nt(const float* __restrict__ p, float w, float* S) {
    floatx4 a = __builtin_nontemporal_load(reinterpret_cast<const floatx4*>(p));
    floatx4 b = __builtin_nontemporal_load(reinterpret_cast<const floatx4*>(p) + 1);
    S[0] += w * a.x; S[1] += w * a.y; S[2] += w * a.z; S[3] += w * a.w;
    S[4] += w * b.x; S[5] += w * b.y; S[6] += w * b.z; S[7] += w * b.w;
}
__device__ __forceinline__ void load8_h(const __half* __restrict__ p, float* o) {
    int4 r = *reinterpret_cast<const int4*>(p);
    const __half2* h = reinterpret_cast<const __half2*>(&r);
    #pragma unroll
    for (int q = 0; q < 4; ++q) {
        float2 f = __half22float2(h[q]);
        o[2 * q + 0] = f.x;
        o[2 * q + 1] = f.y;
    }
}
__device__ __forceinline__ void store8_h(__half* __restrict__ p, const float* v) {
    int4 r;
    __half2* h = reinterpret_cast<__half2*>(&r);
    #pragma unroll
    for (int q = 0; q < 4; ++q)
        h[q] = __floats2half2_rn(v[2 * q + 0], v[2 * q + 1]);
    *reinterpret_cast<int4*>(p) = r;
}

// ---------------------------------------------------------------------------
// Fused propagate over degree-sorted rows: 16 lanes per row (8 dims/lane),
// 4 rows per wave (near-uniform degree), 16 rows per block.
//   MODE 0 (k=1): S = gather_f32(x);  write T1 = S
//   MODE 1 (k=2): S = gather_h(T1);   write T2 = 2S - x (x is f32)
//   MODE 2 (k=3,4): S = gather_h(Tp1); write Tc = 2S - Tp2 (fp16)
//   MODE 3 (k=5): S = gather_h(T4); T5 = 2S - T3;
//                 o = c0*x + c1*T1 + ... + c5*T5; affine -> RMS -> SiLU -> out
// ---------------------------------------------------------------------------
template <int MODE>
__global__ __launch_bounds__(256)
void prop_kernel(const float* __restrict__ xf,
                 const __half* __restrict__ Tp1h,
                 const __half* __restrict__ Tp2h,
                 const int* __restrict__ perm,
                 const int* __restrict__ rowptr2,
                 const int2* __restrict__ epack,
                 const float* __restrict__ cheb,
                 int k,
                 __half* __restrict__ Tch,
                 const __half* __restrict__ T1h,
                 const __half* __restrict__ T2h,
                 float* __restrict__ out,
                 const float* __restrict__ gscale,
                 const float* __restrict__ gbias,
                 const float* __restrict__ rmsw) {
    int grp = threadIdx.x >> 4;                  // 16-lane group id within block
    int sub = threadIdx.x & 15;                  // lane within group
    int i = blockIdx.x * 16 + grp;               // sorted index
    if (i >= N_NODES) return;

    int row = perm[i];
    int beg = rowptr2[i];
    int end = rowptr2[i + 1];
    int d8 = sub * 8;                            // dim offset of this lane

    float S[8] = {0, 0, 0, 0, 0, 0, 0, 0};
    int j = beg;
    for (; j + 3 < end; j += 4) {
        int2 e0 = epack[j], e1 = epack[j + 1], e2 = epack[j + 2], e3 = epack[j + 3];
        float w0 = __int_as_float(e0.y), w1 = __int_as_float(e1.y);
        float w2 = __int_as_float(e2.y), w3 = __int_as_float(e3.y);
        if (MODE == 0) {
            fma8_f_nt(xf + e0.x + d8, w0, S);
            fma8_f_nt(xf + e1.x + d8, w1, S);
            fma8_f_nt(xf + e2.x + d8, w2, S);
            fma8_f_nt(xf + e3.x + d8, w3, S);
        } else {
            fma8_h_nt(Tp1h + e0.x + d8, w0, S);
            fma8_h_nt(Tp1h + e1.x + d8, w1, S);
            fma8_h_nt(Tp1h + e2.x + d8, w2, S);
            fma8_h_nt(Tp1h + e3.x + d8, w3, S);
        }
    }
    for (; j < end; ++j) {
        int2 e0 = epack[j];
        float w = __int_as_float(e0.y);
        if (MODE == 0) fma8_f_nt(xf + e0.x + d8, w, S);
        else           fma8_h_nt(Tp1h + e0.x + d8, w, S);
    }

    size_t off = (size_t)row * HDIM + d8;
    int g = sub >> 2;                            // group index (32 dims per group)

    if (MODE == 0) {
        store8_h(Tch + off, S);
    } else if (MODE == 1) {
        float4 pa = *reinterpret_cast<const float4*>(xf + off);
        float4 pb = *reinterpret_cast<const float4*>(xf + off + 4);
        float t[8];
        t[0] = 2.0f * S[0] - pa.x; t[1] = 2.0f * S[1] - pa.y;
        t[2] = 2.0f * S[2] - pa.z; t[3] = 2.0f * S[3] - pa.w;
        t[4] = 2.0f * S[4] - pb.x; t[5] = 2.0f * S[5] - pb.y;
        t[6] = 2.0f * S[6] - pb.z; t[7] = 2.0f * S[7] - pb.w;
        store8_h(Tch + off, t);
    } else if (MODE == 2) {
        float p[8];
        load8_h(Tp2h + off, p);
        float t[8];
        #pragma unroll
        for (int q = 0; q < 8; ++q) t[q] = 2.0f * S[q] - p[q];
        store8_h(Tch + off, t);
    } else {
        // final: full polynomial sum + epilogue
        float t3[8], t1[8], t2[8], t4[8];
        load8_h(Tp2h + off, t3);       // T3 row
        load8_h(T1h + off, t1);
        load8_h(T2h + off, t2);
        load8_h(Tp1h + off, t4);       // T4 row (gather source this step)
        float4 xa = *reinterpret_cast<const float4*>(xf + off);
        float4 xb = *reinterpret_cast<const float4*>(xf + off + 4);
        float xr[8] = {xa.x, xa.y, xa.z, xa.w, xb.x, xb.y, xb.z, xb.w};

        float c0 = cheb[g * KP1 + 0], c1 = cheb[g * KP1 + 1], c2 = cheb[g * KP1 + 2];
        float c3 = cheb[g * KP1 + 3], c4 = cheb[g * KP1 + 4], c5 = cheb[g * KP1 + 5];
        float sc = gscale[g];
        float bi = gbias[g];

        float o[8];
        float ss = 0.0f;
        #pragma unroll
        for (int q = 0; q < 8; ++q) {
            float t5 = 2.0f * S[q] - t3[q];
            float v = c0 * xr[q] + c1 * t1[q] + c2 * t2[q] + c3 * t3[q]
                    + c4 * t4[q] + c5 * t5;
            v = v * sc + bi;
            o[q] = v;
            ss += v * v;
        }
        // reduce over the 16 lanes of this group (masks 1,2,4,8 stay in-group)
        #pragma unroll
        for (int m = 1; m < 16; m <<= 1)
            ss += __shfl_xor(ss, m, 64);
        float r = rsqrtf(ss * (1.0f / HDIM) + RMS_EPS);

        float4 wa = *reinterpret_cast<const float4*>(rmsw + d8);
        float4 wb = *reinterpret_cast<const float4*>(rmsw + d8 + 4);
        float wv[8] = {wa.x, wa.y, wa.z, wa.w, wb.x, wb.y, wb.z, wb.w};
        float res[8];
        #pragma unroll
        for (int q = 0; q < 8; ++q) {
            float a = o[q] * r * wv[q];
            res[q] = a / (1.0f + expf(-a));
        }
        float4 ra = {res[0], res[1], res[2], res[3]};
        float4 rb = {res[4], res[5], res[6], res[7]};
        *reinterpret_cast<float4*>(out + off) = ra;
        *reinterpret_cast<float4*>(out + off + 4) = rb;
    }
}

// ---------------------------------------------------------------------------
extern "C" void kernel_launch(void* const* d_in, const int* in_sizes, int n_in,
                              void* d_out, int out_size, void* d_ws, size_t ws_size,
                              hipStream_t stream) {
    const float* x      = (const float*)d_in[0];
    const float* ew     = (const float*)d_in[1];
    const float* cheb   = (const float*)d_in[2];
    const float* gscale = (const float*)d_in[3];
    const float* gbias  = (const float*)d_in[4];
    const float* rmsw   = (const float*)d_in[5];
    const int*   eidx   = (const int*)d_in[6];
    const int*   src    = eidx;               // edge_index[0]
    const int*   dst    = eidx + N_EDGES;     // edge_index[1]
    float* out = (float*)d_out;

    // workspace layout
    const size_t NH = (size_t)N_NODES * HDIM;
    __half* T1  = (__half*)d_ws;
    __half* T2  = T1 + NH;
    __half* T3  = T2 + NH;
    __half* T4  = T3 + NH;
    int2*  epack      = (int2*)(T4 + NH);           // E entries
    int*   deg        = (int*)(epack + N_EDGES);
    int*   inc        = deg + N_NODES;
    int*   rowptr2    = inc + N_NODES;              // N+1
    int*   cur2       = rowptr2 + N_NODES + 1;
    int*   perm       = cur2 + N_NODES;
    int*   sortpos    = perm + N_NODES;
    int*   degs_sorted= sortpos + N_NODES;
    int*   blockSums  = degs_sorted + N_NODES;      // 512
    int*   bcount     = blockSums + 512;            // 64
    int*   bcursor    = bcount + NBUCKETS;          // 64

    const int TB = 256;
    const int edge_blocks = (N_EDGES + TB - 1) / TB;    // 1563
    const int node_blocks = (N_NODES + TB - 1) / TB;    // 391
    const int prop_blocks = (N_NODES + 15) / 16;        // 6250

    // ---- degree-sorted CSR build (by destination) ----
    hipMemsetAsync(deg, 0, N_NODES * sizeof(int), stream);
    hipMemsetAsync(bcount, 0, NBUCKETS * sizeof(int), stream);
    hist_kernel<<<edge_blocks, TB, 0, stream>>>(dst, deg);
    bucket_count_kernel<<<node_blocks, TB, 0, stream>>>(deg, bcount);
    bucket_scan_kernel<<<1, NBUCKETS, 0, stream>>>(bcount, bcursor);
    assign_kernel<<<node_blocks, TB, 0, stream>>>(deg, bcursor, perm, sortpos, degs_sorted);
    scan_local_kernel<<<N_SCAN_BLOCKS, SCAN_B, 0, stream>>>(degs_sorted, inc, blockSums);
    scan_blocks_kernel<<<1, 512, 0, stream>>>(blockSums);
    finalize_kernel<<<N_SCAN_BLOCKS, SCAN_B, 0, stream>>>(degs_sorted, inc, blockSums, rowptr2, cur2);
    fill_kernel<<<edge_blocks, TB, 0, stream>>>(src, dst, ew, sortpos, cur2, epack);

    // ---- fused Chebyshev propagates (fp16 intermediates, degree-sorted) ----
    // k=1: T1 = prop(x)
    prop_kernel<0><<<prop_blocks, TB, 0, stream>>>(x, nullptr, nullptr, perm, rowptr2, epack,
                                                   cheb, 1, T1, nullptr, nullptr,
                                                   out, gscale, gbias, rmsw);
    // k=2: T2 = 2*prop(T1) - x
    prop_kernel<1><<<prop_blocks, TB, 0, stream>>>(x, T1, nullptr, perm, rowptr2, epack,
                                                   cheb, 2, T2, nullptr, nullptr,
                                                   out, gscale, gbias, rmsw);
    // k=3: T3 = 2*prop(T2) - T1
    prop_kernel<2><<<prop_blocks, TB, 0, stream>>>(nullptr, T2, T1, perm, rowptr2, epack,
                                                   cheb, 3, T3, nullptr, nullptr,
                                                   out, gscale, gbias, rmsw);
    // k=4: T4 = 2*prop(T3) - T2
    prop_kernel<2><<<prop_blocks, TB, 0, stream>>>(nullptr, T3, T2, perm, rowptr2, epack,
                                                   cheb, 4, T4, nullptr, nullptr,
                                                   out, gscale, gbias, rmsw);
    // k=5: T5 = 2*prop(T4) - T3; out = silu(rms(gaffine(sum c_k T_k)))
    prop_kernel<3><<<prop_blocks, TB, 0, stream>>>(x, T4, T3, perm, rowptr2, epack,
                                                   cheb, 5, nullptr, T1, T2,
                                                   out, gscale, gbias, rmsw);
}

// Round 7
// 273.614 us; speedup vs baseline: 3.9183x; 3.9183x over previous
//
#include <hip/hip_runtime.h>
#include <hip/hip_fp16.h>
#include <math.h>

#define N_NODES 100000
#define N_EDGES 400000
#define HDIM    128
#define KP1     6      // K+1 coefficients per group
#define RMS_EPS 1.1920929e-07f

#define SCAN_B  256
#define N_SCAN_BLOCKS ((N_NODES + SCAN_B - 1) / SCAN_B)   // 391
#define NBUCKETS 64

// native clang vector types for nontemporal builtins
typedef int   intx4   __attribute__((ext_vector_type(4)));
typedef float floatx4 __attribute__((ext_vector_type(4)));

// ---------------------------------------------------------------------------
// degree histogram of destinations
// ---------------------------------------------------------------------------
__global__ void hist_kernel(const int* __restrict__ dst, int* __restrict__ deg) {
    int e = blockIdx.x * blockDim.x + threadIdx.x;
    if (e >= N_EDGES) return;
    atomicAdd(&deg[dst[e]], 1);
}

// ---------------------------------------------------------------------------
// bucket count by degree — per-block LDS histogram, 64 global atomics/block
// ---------------------------------------------------------------------------
__global__ void bucket_count_kernel(const int* __restrict__ deg, int* __restrict__ bcount) {
    __shared__ int lh[NBUCKETS];
    if (threadIdx.x < NBUCKETS) lh[threadIdx.x] = 0;
    __syncthreads();
    int i = blockIdx.x * blockDim.x + threadIdx.x;
    if (i < N_NODES) {
        int d = deg[i];
        int b = d < NBUCKETS ? d : NBUCKETS - 1;
        atomicAdd(&lh[b], 1);
    }
    __syncthreads();
    if (threadIdx.x < NBUCKETS) {
        int c = lh[threadIdx.x];
        if (c) atomicAdd(&bcount[threadIdx.x], c);
    }
}

// ---------------------------------------------------------------------------
// exclusive scan of 64 bucket counts -> bucket cursors (single block)
// ---------------------------------------------------------------------------
__global__ void bucket_scan_kernel(const int* __restrict__ bcount, int* __restrict__ bcursor) {
    __shared__ int lds[NBUCKETS];
    int v = bcount[threadIdx.x];
    lds[threadIdx.x] = v;
    __syncthreads();
    #pragma unroll
    for (int off = 1; off < NBUCKETS; off <<= 1) {
        int t = ((int)threadIdx.x >= off) ? lds[threadIdx.x - off] : 0;
        __syncthreads();
        lds[threadIdx.x] += t;
        __syncthreads();
    }
    bcursor[threadIdx.x] = lds[threadIdx.x] - v;   // exclusive
}

// ---------------------------------------------------------------------------
// counting-sort assignment — LDS local rank + one global atomic per bucket/block
// ---------------------------------------------------------------------------
__global__ void assign_kernel(const int* __restrict__ deg,
                              int* __restrict__ bcursor,
                              int* __restrict__ perm,
                              int* __restrict__ sortpos,
                              int* __restrict__ degs_sorted) {
    __shared__ int lh[NBUCKETS];
    __shared__ int lbase[NBUCKETS];
    if (threadIdx.x < NBUCKETS) lh[threadIdx.x] = 0;
    __syncthreads();
    int i = blockIdx.x * blockDim.x + threadIdx.x;
    int b = 0, lpos = 0, d = 0;
    bool live = (i < N_NODES);
    if (live) {
        d = deg[i];
        b = d < NBUCKETS ? d : NBUCKETS - 1;
        lpos = atomicAdd(&lh[b], 1);           // LDS atomic: cheap
    }
    __syncthreads();
    if (threadIdx.x < NBUCKETS) {
        int c = lh[threadIdx.x];
        lbase[threadIdx.x] = c ? atomicAdd(&bcursor[threadIdx.x], c) : 0;
    }
    __syncthreads();
    if (live) {
        int pos = lbase[b] + lpos;
        perm[pos] = i;
        sortpos[i] = pos;
        degs_sorted[pos] = d;
    }
}

// ---------------------------------------------------------------------------
// per-block inclusive scan of sorted degrees
// ---------------------------------------------------------------------------
__global__ void scan_local_kernel(const int* __restrict__ degs,
                                  int* __restrict__ inc,
                                  int* __restrict__ blockSums) {
    __shared__ int lds[SCAN_B];
    int i = blockIdx.x * SCAN_B + threadIdx.x;
    int v = (i < N_NODES) ? degs[i] : 0;
    lds[threadIdx.x] = v;
    __syncthreads();
    #pragma unroll
    for (int off = 1; off < SCAN_B; off <<= 1) {
        int t = (threadIdx.x >= off) ? lds[threadIdx.x - off] : 0;
        __syncthreads();
        lds[threadIdx.x] += t;
        __syncthreads();
    }
    if (i < N_NODES) inc[i] = lds[threadIdx.x];
    if (threadIdx.x == SCAN_B - 1) blockSums[blockIdx.x] = lds[SCAN_B - 1];
}

// ---------------------------------------------------------------------------
// exclusive scan of the 391 block sums (single block)
// ---------------------------------------------------------------------------
__global__ void scan_blocks_kernel(int* __restrict__ blockSums) {
    __shared__ int lds[512];
    int v = (threadIdx.x < N_SCAN_BLOCKS) ? blockSums[threadIdx.x] : 0;
    lds[threadIdx.x] = v;
    __syncthreads();
    #pragma unroll
    for (int off = 1; off < 512; off <<= 1) {
        int t = ((int)threadIdx.x >= off) ? lds[threadIdx.x - off] : 0;
        __syncthreads();
        lds[threadIdx.x] += t;
        __syncthreads();
    }
    if (threadIdx.x < N_SCAN_BLOCKS)
        blockSums[threadIdx.x] = (threadIdx.x == 0) ? 0 : lds[threadIdx.x - 1];
}

// ---------------------------------------------------------------------------
// rowptr2 (exclusive, sorted order) + cursor copy
// ---------------------------------------------------------------------------
__global__ void finalize_kernel(const int* __restrict__ degs_sorted,
                                const int* __restrict__ inc,
                                const int* __restrict__ blockSums,
                                int* __restrict__ rowptr2,
                                int* __restrict__ cur2) {
    int i = blockIdx.x * SCAN_B + threadIdx.x;
    if (i >= N_NODES) return;
    int ex = inc[i] - degs_sorted[i] + blockSums[i >> 8];
    rowptr2[i] = ex;
    cur2[i] = ex;
    if (i == 0) rowptr2[N_NODES] = N_EDGES;
}

// ---------------------------------------------------------------------------
// fill packed (src_row_offset, weight), edge slots contiguous in sorted order
// ---------------------------------------------------------------------------
__global__ void fill_kernel(const int* __restrict__ src,
                            const int* __restrict__ dst,
                            const float* __restrict__ ew,
                            const int* __restrict__ sortpos,
                            int* __restrict__ cur2,
                            int2* __restrict__ epack) {
    int e = blockIdx.x * blockDim.x + threadIdx.x;
    if (e >= N_EDGES) return;
    int sp = sortpos[dst[e]];
    int pos = atomicAdd(&cur2[sp], 1);
    int2 p;
    p.x = src[e] * HDIM;                 // element offset of source row
    p.y = __float_as_int(ew[e]);
    epack[pos] = p;
}

// ---------------------------------------------------------------------------
// helpers: 8-dim fragments per lane; gathers use non-temporal loads
// ---------------------------------------------------------------------------
__device__ __forceinline__ void fma8_h_nt(const __half* __restrict__ p, float w, float* S) {
    intx4 r = __builtin_nontemporal_load(reinterpret_cast<const intx4*>(p));
    union { intx4 v; __half2 h[4]; } u;
    u.v = r;
    #pragma unroll
    for (int q = 0; q < 4; ++q) {
        float2 f = __half22float2(u.h[q]);
        S[2 * q + 0] += w * f.x;
        S[2 * q + 1] += w * f.y;
    }
}
__device__ __forceinline__ void fma8_f_nt(const float* __restrict__ p, float w, float* S) {
    floatx4 a = __builtin_nontemporal_load(reinterpret_cast<const floatx4*>(p));
    floatx4 b = __builtin_nontemporal_load(reinterpret_cast<const floatx4*>(p) + 1);
    S[0] += w * a.x; S[1] += w * a.y; S[2] += w * a.z; S[3] += w * a.w;
    S[4] += w * b.x; S[5] += w * b.y; S[6] += w * b.z; S[7] += w * b.w;
}
__device__ __forceinline__ void load8_h(const __half* __restrict__ p, float* o) {
    int4 r = *reinterpret_cast<const int4*>(p);
    const __half2* h = reinterpret_cast<const __half2*>(&r);
    #pragma unroll
    for (int q = 0; q < 4; ++q) {
        float2 f = __half22float2(h[q]);
        o[2 * q + 0] = f.x;
        o[2 * q + 1] = f.y;
    }
}
__device__ __forceinline__ void store8_h(__half* __restrict__ p, const float* v) {
    int4 r;
    __half2* h = reinterpret_cast<__half2*>(&r);
    #pragma unroll
    for (int q = 0; q < 4; ++q)
        h[q] = __floats2half2_rn(v[2 * q + 0], v[2 * q + 1]);
    *reinterpret_cast<int4*>(p) = r;
}

// ---------------------------------------------------------------------------
// Fused propagate over degree-sorted rows: 16 lanes per row (8 dims/lane),
// 4 rows per wave (near-uniform degree), 16 rows per block.
//   MODE 0 (k=1): S = gather_f32(x);  write T1 = S
//   MODE 1 (k=2): S = gather_h(T1);   write T2 = 2S - x (x is f32)
//   MODE 2 (k=3,4): S = gather_h(Tp1); write Tc = 2S - Tp2 (fp16)
//   MODE 3 (k=5): S = gather_h(T4); T5 = 2S - T3;
//                 o = c0*x + c1*T1 + ... + c5*T5; affine -> RMS -> SiLU -> out
// ---------------------------------------------------------------------------
template <int MODE>
__global__ __launch_bounds__(256)
void prop_kernel(const float* __restrict__ xf,
                 const __half* __restrict__ Tp1h,
                 const __half* __restrict__ Tp2h,
                 const int* __restrict__ perm,
                 const int* __restrict__ rowptr2,
                 const int2* __restrict__ epack,
                 const float* __restrict__ cheb,
                 int k,
                 __half* __restrict__ Tch,
                 const __half* __restrict__ T1h,
                 const __half* __restrict__ T2h,
                 float* __restrict__ out,
                 const float* __restrict__ gscale,
                 const float* __restrict__ gbias,
                 const float* __restrict__ rmsw) {
    int grp = threadIdx.x >> 4;                  // 16-lane group id within block
    int sub = threadIdx.x & 15;                  // lane within group
    int i = blockIdx.x * 16 + grp;               // sorted index
    if (i >= N_NODES) return;

    int row = perm[i];
    int beg = rowptr2[i];
    int end = rowptr2[i + 1];
    int d8 = sub * 8;                            // dim offset of this lane

    float S[8] = {0, 0, 0, 0, 0, 0, 0, 0};
    int j = beg;
    for (; j + 3 < end; j += 4) {
        int2 e0 = epack[j], e1 = epack[j + 1], e2 = epack[j + 2], e3 = epack[j + 3];
        float w0 = __int_as_float(e0.y), w1 = __int_as_float(e1.y);
        float w2 = __int_as_float(e2.y), w3 = __int_as_float(e3.y);
        if (MODE == 0) {
            fma8_f_nt(xf + e0.x + d8, w0, S);
            fma8_f_nt(xf + e1.x + d8, w1, S);
            fma8_f_nt(xf + e2.x + d8, w2, S);
            fma8_f_nt(xf + e3.x + d8, w3, S);
        } else {
            fma8_h_nt(Tp1h + e0.x + d8, w0, S);
            fma8_h_nt(Tp1h + e1.x + d8, w1, S);
            fma8_h_nt(Tp1h + e2.x + d8, w2, S);
            fma8_h_nt(Tp1h + e3.x + d8, w3, S);
        }
    }
    for (; j < end; ++j) {
        int2 e0 = epack[j];
        float w = __int_as_float(e0.y);
        if (MODE == 0) fma8_f_nt(xf + e0.x + d8, w, S);
        else           fma8_h_nt(Tp1h + e0.x + d8, w, S);
    }

    size_t off = (size_t)row * HDIM + d8;
    int g = sub >> 2;                            // group index (32 dims per group)

    if (MODE == 0) {
        store8_h(Tch + off, S);
    } else if (MODE == 1) {
        float4 pa = *reinterpret_cast<const float4*>(xf + off);
        float4 pb = *reinterpret_cast<const float4*>(xf + off + 4);
        float t[8];
        t[0] = 2.0f * S[0] - pa.x; t[1] = 2.0f * S[1] - pa.y;
        t[2] = 2.0f * S[2] - pa.z; t[3] = 2.0f * S[3] - pa.w;
        t[4] = 2.0f * S[4] - pb.x; t[5] = 2.0f * S[5] - pb.y;
        t[6] = 2.0f * S[6] - pb.z; t[7] = 2.0f * S[7] - pb.w;
        store8_h(Tch + off, t);
    } else if (MODE == 2) {
        float p[8];
        load8_h(Tp2h + off, p);
        float t[8];
        #pragma unroll
        for (int q = 0; q < 8; ++q) t[q] = 2.0f * S[q] - p[q];
        store8_h(Tch + off, t);
    } else {
        // final: full polynomial sum + epilogue
        float t3[8], t1[8], t2[8], t4[8];
        load8_h(Tp2h + off, t3);       // T3 row
        load8_h(T1h + off, t1);
        load8_h(T2h + off, t2);
        load8_h(Tp1h + off, t4);       // T4 row (gather source this step)
        float4 xa = *reinterpret_cast<const float4*>(xf + off);
        float4 xb = *reinterpret_cast<const float4*>(xf + off + 4);
        float xr[8] = {xa.x, xa.y, xa.z, xa.w, xb.x, xb.y, xb.z, xb.w};

        float c0 = cheb[g * KP1 + 0], c1 = cheb[g * KP1 + 1], c2 = cheb[g * KP1 + 2];
        float c3 = cheb[g * KP1 + 3], c4 = cheb[g * KP1 + 4], c5 = cheb[g * KP1 + 5];
        float sc = gscale[g];
        float bi = gbias[g];

        float o[8];
        float ss = 0.0f;
        #pragma unroll
        for (int q = 0; q < 8; ++q) {
            float t5 = 2.0f * S[q] - t3[q];
            float v = c0 * xr[q] + c1 * t1[q] + c2 * t2[q] + c3 * t3[q]
                    + c4 * t4[q] + c5 * t5;
            v = v * sc + bi;
            o[q] = v;
            ss += v * v;
        }
        // reduce over the 16 lanes of this group (masks 1,2,4,8 stay in-group)
        #pragma unroll
        for (int m = 1; m < 16; m <<= 1)
            ss += __shfl_xor(ss, m, 64);
        float r = rsqrtf(ss * (1.0f / HDIM) + RMS_EPS);

        float4 wa = *reinterpret_cast<const float4*>(rmsw + d8);
        float4 wb = *reinterpret_cast<const float4*>(rmsw + d8 + 4);
        float wv[8] = {wa.x, wa.y, wa.z, wa.w, wb.x, wb.y, wb.z, wb.w};
        float res[8];
        #pragma unroll
        for (int q = 0; q < 8; ++q) {
            float a = o[q] * r * wv[q];
            res[q] = a / (1.0f + expf(-a));
        }
        float4 ra = {res[0], res[1], res[2], res[3]};
        float4 rb = {res[4], res[5], res[6], res[7]};
        *reinterpret_cast<float4*>(out + off) = ra;
        *reinterpret_cast<float4*>(out + off + 4) = rb;
    }
}

// ---------------------------------------------------------------------------
extern "C" void kernel_launch(void* const* d_in, const int* in_sizes, int n_in,
                              void* d_out, int out_size, void* d_ws, size_t ws_size,
                              hipStream_t stream) {
    const float* x      = (const float*)d_in[0];
    const float* ew     = (const float*)d_in[1];
    const float* cheb   = (const float*)d_in[2];
    const float* gscale = (const float*)d_in[3];
    const float* gbias  = (const float*)d_in[4];
    const float* rmsw   = (const float*)d_in[5];
    const int*   eidx   = (const int*)d_in[6];
    const int*   src    = eidx;               // edge_index[0]
    const int*   dst    = eidx + N_EDGES;     // edge_index[1]
    float* out = (float*)d_out;

    // workspace layout
    const size_t NH = (size_t)N_NODES * HDIM;
    __half* T1  = (__half*)d_ws;
    __half* T2  = T1 + NH;
    __half* T3  = T2 + NH;
    __half* T4  = T3 + NH;
    int2*  epack      = (int2*)(T4 + NH);           // E entries
    int*   deg        = (int*)(epack + N_EDGES);
    int*   inc        = deg + N_NODES;
    int*   rowptr2    = inc + N_NODES;              // N+1
    int*   cur2       = rowptr2 + N_NODES + 1;
    int*   perm       = cur2 + N_NODES;
    int*   sortpos    = perm + N_NODES;
    int*   degs_sorted= sortpos + N_NODES;
    int*   blockSums  = degs_sorted + N_NODES;      // 512
    int*   bcount     = blockSums + 512;            // 64
    int*   bcursor    = bcount + NBUCKETS;          // 64

    const int TB = 256;
    const int edge_blocks = (N_EDGES + TB - 1) / TB;    // 1563
    const int node_blocks = (N_NODES + TB - 1) / TB;    // 391
    const int prop_blocks = (N_NODES + 15) / 16;        // 6250

    // ---- degree-sorted CSR build (by destination) ----
    hipMemsetAsync(deg, 0, N_NODES * sizeof(int), stream);
    hipMemsetAsync(bcount, 0, NBUCKETS * sizeof(int), stream);
    hist_kernel<<<edge_blocks, TB, 0, stream>>>(dst, deg);
    bucket_count_kernel<<<node_blocks, TB, 0, stream>>>(deg, bcount);
    bucket_scan_kernel<<<1, NBUCKETS, 0, stream>>>(bcount, bcursor);
    assign_kernel<<<node_blocks, TB, 0, stream>>>(deg, bcursor, perm, sortpos, degs_sorted);
    scan_local_kernel<<<N_SCAN_BLOCKS, SCAN_B, 0, stream>>>(degs_sorted, inc, blockSums);
    scan_blocks_kernel<<<1, 512, 0, stream>>>(blockSums);
    finalize_kernel<<<N_SCAN_BLOCKS, SCAN_B, 0, stream>>>(degs_sorted, inc, blockSums, rowptr2, cur2);
    fill_kernel<<<edge_blocks, TB, 0, stream>>>(src, dst, ew, sortpos, cur2, epack);

    // ---- fused Chebyshev propagates (fp16 intermediates, degree-sorted) ----
    // k=1: T1 = prop(x)
    prop_kernel<0><<<prop_blocks, TB, 0, stream>>>(x, nullptr, nullptr, perm, rowptr2, epack,
                                                   cheb, 1, T1, nullptr, nullptr,
                                                   out, gscale, gbias, rmsw);
    // k=2: T2 = 2*prop(T1) - x
    prop_kernel<1><<<prop_blocks, TB, 0, stream>>>(x, T1, nullptr, perm, rowptr2, epack,
                                                   cheb, 2, T2, nullptr, nullptr,
                                                   out, gscale, gbias, rmsw);
    // k=3: T3 = 2*prop(T2) - T1
    prop_kernel<2><<<prop_blocks, TB, 0, stream>>>(nullptr, T2, T1, perm, rowptr2, epack,
                                                   cheb, 3, T3, nullptr, nullptr,
                                                   out, gscale, gbias, rmsw);
    // k=4: T4 = 2*prop(T3) - T2
    prop_kernel<2><<<prop_blocks, TB, 0, stream>>>(nullptr, T3, T2, perm, rowptr2, epack,
                                                   cheb, 4, T4, nullptr, nullptr,
                                                   out, gscale, gbias, rmsw);
    // k=5: T5 = 2*prop(T4) - T3; out = silu(rms(gaffine(sum c_k T_k)))
    prop_kernel<3><<<prop_blocks, TB, 0, stream>>>(x, T4, T3, perm, rowptr2, epack,
                                                   cheb, 5, nullptr, T1, T2,
                                                   out, gscale, gbias, rmsw);
}

// Round 8
// 201.858 us; speedup vs baseline: 5.3112x; 1.3555x over previous
//
#include <hip/hip_runtime.h>
#include <hip/hip_fp16.h>
#include <math.h>

#define N_NODES 100000
#define N_EDGES 400000
#define HDIM    128
#define KP1     6      // K+1 coefficients per group
#define RMS_EPS 1.1920929e-07f

#define SCAN_B  256
#define N_SCAN_BLOCKS ((N_NODES + SCAN_B - 1) / SCAN_B)   // 391

// ---------------------------------------------------------------------------
// x -> fp16 copy (vectorized, 8 elems/thread)
// ---------------------------------------------------------------------------
__global__ __launch_bounds__(256)
void x2h_kernel(const float* __restrict__ x, __half* __restrict__ xh) {
    size_t i = (size_t)blockIdx.x * blockDim.x + threadIdx.x;
    const size_t total = (size_t)N_NODES * HDIM / 8;
    if (i >= total) return;
    const float4 a = reinterpret_cast<const float4*>(x)[2 * i];
    const float4 b = reinterpret_cast<const float4*>(x)[2 * i + 1];
    int4 r;
    __half2* h = reinterpret_cast<__half2*>(&r);
    h[0] = __floats2half2_rn(a.x, a.y);
    h[1] = __floats2half2_rn(a.z, a.w);
    h[2] = __floats2half2_rn(b.x, b.y);
    h[3] = __floats2half2_rn(b.z, b.w);
    reinterpret_cast<int4*>(xh)[i] = r;
}

// ---------------------------------------------------------------------------
// CSR build step 1: histogram of destination degrees
// ---------------------------------------------------------------------------
__global__ void hist_kernel(const int* __restrict__ dst, int* __restrict__ deg) {
    int e = blockIdx.x * blockDim.x + threadIdx.x;
    if (e >= N_EDGES) return;
    atomicAdd(&deg[dst[e]], 1);
}

// ---------------------------------------------------------------------------
// CSR build step 2a: per-block inclusive scan of deg
// ---------------------------------------------------------------------------
__global__ void scan_local_kernel(const int* __restrict__ deg,
                                  int* __restrict__ inc,
                                  int* __restrict__ blockSums) {
    __shared__ int lds[SCAN_B];
    int i = blockIdx.x * SCAN_B + threadIdx.x;
    int v = (i < N_NODES) ? deg[i] : 0;
    lds[threadIdx.x] = v;
    __syncthreads();
    #pragma unroll
    for (int off = 1; off < SCAN_B; off <<= 1) {
        int t = (threadIdx.x >= off) ? lds[threadIdx.x - off] : 0;
        __syncthreads();
        lds[threadIdx.x] += t;
        __syncthreads();
    }
    if (i < N_NODES) inc[i] = lds[threadIdx.x];
    if (threadIdx.x == SCAN_B - 1) blockSums[blockIdx.x] = lds[SCAN_B - 1];
}

// ---------------------------------------------------------------------------
// CSR build step 2b: exclusive scan of the 391 block sums (single block)
// ---------------------------------------------------------------------------
__global__ void scan_blocks_kernel(int* __restrict__ blockSums) {
    __shared__ int lds[512];
    int v = (threadIdx.x < N_SCAN_BLOCKS) ? blockSums[threadIdx.x] : 0;
    lds[threadIdx.x] = v;
    __syncthreads();
    #pragma unroll
    for (int off = 1; off < 512; off <<= 1) {
        int t = ((int)threadIdx.x >= off) ? lds[threadIdx.x - off] : 0;
        __syncthreads();
        lds[threadIdx.x] += t;
        __syncthreads();
    }
    if (threadIdx.x < N_SCAN_BLOCKS)
        blockSums[threadIdx.x] = (threadIdx.x == 0) ? 0 : lds[threadIdx.x - 1];
}

// ---------------------------------------------------------------------------
// CSR build step 2c: rowptr (exclusive) + cursor copy
// ---------------------------------------------------------------------------
__global__ void finalize_kernel(const int* __restrict__ deg,
                                const int* __restrict__ inc,
                                const int* __restrict__ blockSums,
                                int* __restrict__ rowptr,
                                int* __restrict__ cursor) {
    int i = blockIdx.x * SCAN_B + threadIdx.x;
    if (i >= N_NODES) return;
    int ex = inc[i] - deg[i] + blockSums[i >> 8];
    rowptr[i] = ex;
    cursor[i] = ex;
    if (i == 0) rowptr[N_NODES] = N_EDGES;
}

// ---------------------------------------------------------------------------
// CSR build step 3: fill packed (src_row_offset, weight) per slot
// ---------------------------------------------------------------------------
__global__ void fill_kernel(const int* __restrict__ src,
                            const int* __restrict__ dst,
                            const float* __restrict__ ew,
                            int* __restrict__ cursor,
                            int2* __restrict__ epack) {
    int e = blockIdx.x * blockDim.x + threadIdx.x;
    if (e >= N_EDGES) return;
    int d = dst[e];
    int pos = atomicAdd(&cursor[d], 1);
    int2 p;
    p.x = src[e] * HDIM;                 // element offset of source row
    p.y = __float_as_int(ew[e]);
    epack[pos] = p;
}

// ---------------------------------------------------------------------------
// helpers: 8-dim fp16 fragments per lane (regular cached loads)
// ---------------------------------------------------------------------------
__device__ __forceinline__ void fma8_h(const __half* __restrict__ p, float w, float* S) {
    int4 r = *reinterpret_cast<const int4*>(p);       // 8 halves
    const __half2* h = reinterpret_cast<const __half2*>(&r);
    #pragma unroll
    for (int q = 0; q < 4; ++q) {
        float2 f = __half22float2(h[q]);
        S[2 * q + 0] += w * f.x;
        S[2 * q + 1] += w * f.y;
    }
}
__device__ __forceinline__ void load8_h(const __half* __restrict__ p, float* o) {
    int4 r = *reinterpret_cast<const int4*>(p);
    const __half2* h = reinterpret_cast<const __half2*>(&r);
    #pragma unroll
    for (int q = 0; q < 4; ++q) {
        float2 f = __half22float2(h[q]);
        o[2 * q + 0] = f.x;
        o[2 * q + 1] = f.y;
    }
}
__device__ __forceinline__ void store8_h(__half* __restrict__ p, const float* v) {
    int4 r;
    __half2* h = reinterpret_cast<__half2*>(&r);
    #pragma unroll
    for (int q = 0; q < 4; ++q)
        h[q] = __floats2half2_rn(v[2 * q + 0], v[2 * q + 1]);
    *reinterpret_cast<int4*>(p) = r;
}

// ---------------------------------------------------------------------------
// Fused propagate: 16 lanes per node (8 dims/lane), 4 nodes per wave,
// 16 nodes per 256-thread block; 4x unrolled fp16 gathers (16B/lane).
//   MODE 0 (k=1):     S = gather(xh);  write T1 = S
//   MODE 1 (k=2,3,4): S = gather(Tp1); write Tc = 2S - Tp2
//   MODE 2 (k=5):     S = gather(T4);  T5 = 2S - T3;
//                     o = c0*xh + c1*T1 + ... + c5*T5;
//                     group affine -> RMSNorm -> SiLU -> out (f32)
// ---------------------------------------------------------------------------
template <int MODE>
__global__ __launch_bounds__(256)
void prop_kernel(const __half* __restrict__ Tp1h,   // gather source
                 const __half* __restrict__ Tp2h,
                 const __half* __restrict__ xh,     // MODE 2 only
                 const int* __restrict__ rowptr,
                 const int2* __restrict__ epack,
                 const float* __restrict__ cheb,
                 __half* __restrict__ Tch,
                 const __half* __restrict__ T1h,    // MODE 2 only
                 const __half* __restrict__ T2h,    // MODE 2 only
                 float* __restrict__ out,
                 const float* __restrict__ gscale,
                 const float* __restrict__ gbias,
                 const float* __restrict__ rmsw) {
    int grp = threadIdx.x >> 4;                  // 16-lane group id within block
    int sub = threadIdx.x & 15;                  // lane within group
    int row = blockIdx.x * 16 + grp;
    if (row >= N_NODES) return;

    int beg = rowptr[row];
    int end = rowptr[row + 1];
    int d8 = sub * 8;                            // dim offset of this lane

    float S[8] = {0, 0, 0, 0, 0, 0, 0, 0};
    int j = beg;
    for (; j + 3 < end; j += 4) {
        int2 e0 = epack[j], e1 = epack[j + 1], e2 = epack[j + 2], e3 = epack[j + 3];
        float w0 = __int_as_float(e0.y), w1 = __int_as_float(e1.y);
        float w2 = __int_as_float(e2.y), w3 = __int_as_float(e3.y);
        fma8_h(Tp1h + e0.x + d8, w0, S);
        fma8_h(Tp1h + e1.x + d8, w1, S);
        fma8_h(Tp1h + e2.x + d8, w2, S);
        fma8_h(Tp1h + e3.x + d8, w3, S);
    }
    for (; j < end; ++j) {
        int2 e0 = epack[j];
        float w = __int_as_float(e0.y);
        fma8_h(Tp1h + e0.x + d8, w, S);
    }

    size_t off = (size_t)row * HDIM + d8;
    int g = sub >> 2;                            // group index (32 dims per group)

    if (MODE == 0) {
        store8_h(Tch + off, S);
    } else if (MODE == 1) {
        float p[8];
        load8_h(Tp2h + off, p);
        float t[8];
        #pragma unroll
        for (int q = 0; q < 8; ++q) t[q] = 2.0f * S[q] - p[q];
        store8_h(Tch + off, t);
    } else {
        // final: full polynomial sum + epilogue
        float t3[8], t1[8], t2[8], t4[8], xr[8];
        load8_h(Tp2h + off, t3);       // T3 row
        load8_h(T1h + off, t1);
        load8_h(T2h + off, t2);
        load8_h(Tp1h + off, t4);       // T4 row (gather source this step)
        load8_h(xh + off, xr);

        float c0 = cheb[g * KP1 + 0], c1 = cheb[g * KP1 + 1], c2 = cheb[g * KP1 + 2];
        float c3 = cheb[g * KP1 + 3], c4 = cheb[g * KP1 + 4], c5 = cheb[g * KP1 + 5];
        float sc = gscale[g];
        float bi = gbias[g];

        float o[8];
        float ss = 0.0f;
        #pragma unroll
        for (int q = 0; q < 8; ++q) {
            float t5 = 2.0f * S[q] - t3[q];
            float v = c0 * xr[q] + c1 * t1[q] + c2 * t2[q] + c3 * t3[q]
                    + c4 * t4[q] + c5 * t5;
            v = v * sc + bi;
            o[q] = v;
            ss += v * v;
        }
        // reduce over the 16 lanes of this group (masks 1,2,4,8 stay in-group)
        #pragma unroll
        for (int m = 1; m < 16; m <<= 1)
            ss += __shfl_xor(ss, m, 64);
        float r = rsqrtf(ss * (1.0f / HDIM) + RMS_EPS);

        float4 wa = *reinterpret_cast<const float4*>(rmsw + d8);
        float4 wb = *reinterpret_cast<const float4*>(rmsw + d8 + 4);
        float wv[8] = {wa.x, wa.y, wa.z, wa.w, wb.x, wb.y, wb.z, wb.w};
        float res[8];
        #pragma unroll
        for (int q = 0; q < 8; ++q) {
            float a = o[q] * r * wv[q];
            res[q] = a / (1.0f + expf(-a));
        }
        float4 ra = {res[0], res[1], res[2], res[3]};
        float4 rb = {res[4], res[5], res[6], res[7]};
        *reinterpret_cast<float4*>(out + off) = ra;
        *reinterpret_cast<float4*>(out + off + 4) = rb;
    }
}

// ---------------------------------------------------------------------------
extern "C" void kernel_launch(void* const* d_in, const int* in_sizes, int n_in,
                              void* d_out, int out_size, void* d_ws, size_t ws_size,
                              hipStream_t stream) {
    const float* x      = (const float*)d_in[0];
    const float* ew     = (const float*)d_in[1];
    const float* cheb   = (const float*)d_in[2];
    const float* gscale = (const float*)d_in[3];
    const float* gbias  = (const float*)d_in[4];
    const float* rmsw   = (const float*)d_in[5];
    const int*   eidx   = (const int*)d_in[6];
    const int*   src    = eidx;               // edge_index[0]
    const int*   dst    = eidx + N_EDGES;     // edge_index[1]
    float* out = (float*)d_out;

    // workspace layout
    const size_t NH = (size_t)N_NODES * HDIM;
    __half* xh  = (__half*)d_ws;
    __half* T1  = xh + NH;
    __half* T2  = T1 + NH;
    __half* T3  = T2 + NH;
    __half* T4  = T3 + NH;
    int2*  epack    = (int2*)(T4 + NH);           // E entries (8B aligned)
    int*   deg      = (int*)(epack + N_EDGES);
    int*   inc      = deg + N_NODES;
    int*   rowptr   = inc + N_NODES;              // N+1
    int*   cursor   = rowptr + N_NODES + 1;
    int*   blockSums= cursor + N_NODES;           // 512

    const int TB = 256;
    const int edge_blocks = (N_EDGES + TB - 1) / TB;    // 1563
    const int conv_blocks = (int)((NH / 8 + TB - 1) / TB); // 6250
    const int prop_blocks = (N_NODES + 15) / 16;        // 6250

    // ---- x -> fp16 + CSR build (by destination) ----
    x2h_kernel<<<conv_blocks, TB, 0, stream>>>(x, xh);
    hipMemsetAsync(deg, 0, N_NODES * sizeof(int), stream);
    hist_kernel<<<edge_blocks, TB, 0, stream>>>(dst, deg);
    scan_local_kernel<<<N_SCAN_BLOCKS, SCAN_B, 0, stream>>>(deg, inc, blockSums);
    scan_blocks_kernel<<<1, 512, 0, stream>>>(blockSums);
    finalize_kernel<<<N_SCAN_BLOCKS, SCAN_B, 0, stream>>>(deg, inc, blockSums, rowptr, cursor);
    fill_kernel<<<edge_blocks, TB, 0, stream>>>(src, dst, ew, cursor, epack);

    // ---- fused Chebyshev propagates (all fp16) ----
    // k=1: T1 = prop(xh)
    prop_kernel<0><<<prop_blocks, TB, 0, stream>>>(xh, nullptr, nullptr, rowptr, epack,
                                                   cheb, T1, nullptr, nullptr,
                                                   out, gscale, gbias, rmsw);
    // k=2: T2 = 2*prop(T1) - xh
    prop_kernel<1><<<prop_blocks, TB, 0, stream>>>(T1, xh, nullptr, rowptr, epack,
                                                   cheb, T2, nullptr, nullptr,
                                                   out, gscale, gbias, rmsw);
    // k=3: T3 = 2*prop(T2) - T1
    prop_kernel<1><<<prop_blocks, TB, 0, stream>>>(T2, T1, nullptr, rowptr, epack,
                                                   cheb, T3, nullptr, nullptr,
                                                   out, gscale, gbias, rmsw);
    // k=4: T4 = 2*prop(T3) - T2
    prop_kernel<1><<<prop_blocks, TB, 0, stream>>>(T3, T2, nullptr, rowptr, epack,
                                                   cheb, T4, nullptr, nullptr,
                                                   out, gscale, gbias, rmsw);
    // k=5: T5 = 2*prop(T4) - T3; out = silu(rms(gaffine(sum c_k T_k)))
    prop_kernel<2><<<prop_blocks, TB, 0, stream>>>(T4, T3, xh, rowptr, epack,
                                                   cheb, nullptr, T1, T2,
                                                   out, gscale, gbias, rmsw);
}